// Round 2
// baseline (5359.252 us; speedup 1.0000x reference)
//
#include <hip/hip_runtime.h>
#include <hip/hip_bf16.h>

#define HID 64
#define MSG 128
#define NDIM 32
#define EDIM 16
#define NG 512

typedef unsigned short u16;

__device__ __forceinline__ float b2f(u16 u) {
    union { unsigned int i; float f; } v; v.i = ((unsigned int)u) << 16; return v.f;
}
__device__ __forceinline__ u16 f2b(float f) {
    union { float f; unsigned int i; } v; v.f = f;
    unsigned int r = v.i + 0x7FFF + ((v.i >> 16) & 1);
    return (u16)(r >> 16);
}
__device__ __forceinline__ float sigm(float x) { return 1.0f / (1.0f + expf(-x)); }

// ---------------- CSR build ----------------
__global__ void k_hist(const int* __restrict__ idx, int n, int* __restrict__ cnt) {
    int i = blockIdx.x * blockDim.x + threadIdx.x;
    int stride = gridDim.x * blockDim.x;
    for (; i < n; i += stride) atomicAdd(&cnt[idx[i]], 1);
}

// single-block exclusive scan, out[n] = total
__global__ void k_scan(const int* __restrict__ in, int* __restrict__ out, int n) {
    __shared__ int sh[1024];
    int tid = threadIdx.x;
    int carry = 0;
    for (int base = 0; base < n; base += 1024) {
        int i = base + tid;
        int v = (i < n) ? in[i] : 0;
        sh[tid] = v;
        __syncthreads();
        for (int off = 1; off < 1024; off <<= 1) {
            int t = (tid >= off) ? sh[tid - off] : 0;
            __syncthreads();
            sh[tid] += t;
            __syncthreads();
        }
        if (i < n) out[i] = sh[tid] - v + carry;
        carry += sh[1023];
        __syncthreads();
    }
    if (tid == 0) out[n] = carry;
}

__global__ void k_scatter(const int* __restrict__ src, const int* __restrict__ dst, int n,
                          const int* __restrict__ ptr, int* __restrict__ cursor,
                          int* __restrict__ elist, int* __restrict__ slist) {
    int i = blockIdx.x * blockDim.x + threadIdx.x;
    int stride = gridDim.x * blockDim.x;
    for (; i < n; i += stride) {
        int d = dst[i];
        int pos = ptr[d] + atomicAdd(&cursor[d], 1);
        elist[pos] = i;
        slist[pos] = src[i];
    }
}

// ---------------- node embedding: xh = x_feat @ W_emb + b_emb ----------------
__global__ void k_embed(const float* __restrict__ xf, const float* __restrict__ We,
                        const float* __restrict__ be, float* __restrict__ xh, int N) {
    __shared__ float Wl[NDIM * HID];
    for (int t = threadIdx.x; t < NDIM * HID; t += blockDim.x) Wl[t] = We[t];
    __syncthreads();
    int total = N * HID;
    int stride = gridDim.x * blockDim.x;
    for (int idx = blockIdx.x * blockDim.x + threadIdx.x; idx < total; idx += stride) {
        int n = idx >> 6, c = idx & 63;
        const float* xr = xf + n * NDIM;
        float acc = be[c];
#pragma unroll
        for (int k = 0; k < NDIM; k++) acc += xr[k] * Wl[k * HID + c];
        xh[idx] = acc;
    }
}

// ---------------- Ps = x @ W1s  (W_m1 rows 64..127), block = 128 ----------------
__global__ void k_ps(const float* __restrict__ xh, const float* __restrict__ Wm1,
                     float* __restrict__ Ps, int N) {
    __shared__ float Ws[HID * MSG];
    __shared__ float xr[HID];
    for (int t = threadIdx.x; t < HID * MSG; t += blockDim.x) Ws[t] = Wm1[HID * MSG + t];
    __syncthreads();
    int tid = threadIdx.x;
    for (int d = blockIdx.x; d < N; d += gridDim.x) {
        if (tid < HID) xr[tid] = xh[(size_t)d * HID + tid];
        __syncthreads();
        float acc = 0.f;
#pragma unroll
        for (int k = 0; k < HID; k++) acc += xr[k] * Ws[k * MSG + tid];
        Ps[(size_t)d * MSG + tid] = acc;
        __syncthreads();
    }
}

// ---------------- per-node edge aggregation: H[d] = sum_e relu(Pd + Ps[src] + W1e@ea + b1), block = 128
__global__ void k_edge(const float* __restrict__ xh, const float* __restrict__ Ps,
                       const float* __restrict__ ea, const float* __restrict__ Wm1,
                       const float* __restrict__ bm1,
                       const int* __restrict__ ptr, const int* __restrict__ elist,
                       const int* __restrict__ slist, float* __restrict__ H, int N) {
    __shared__ float Wd[HID * MSG];   // W_m1 rows 0..63 (dst part)
    __shared__ float We[EDIM * MSG];  // W_m1 rows 128..143 (edge part)
    __shared__ float b1[MSG];
    __shared__ float xr[HID];
    for (int t = threadIdx.x; t < HID * MSG; t += blockDim.x) Wd[t] = Wm1[t];
    for (int t = threadIdx.x; t < EDIM * MSG; t += blockDim.x) We[t] = Wm1[MSG * MSG + t];
    for (int t = threadIdx.x; t < MSG; t += blockDim.x) b1[t] = bm1[t];
    __syncthreads();
    int tid = threadIdx.x;
    int lane = tid & 63;
    for (int d = blockIdx.x; d < N; d += gridDim.x) {
        if (tid < HID) xr[tid] = xh[(size_t)d * HID + tid];
        __syncthreads();
        float pd = b1[tid];
#pragma unroll
        for (int k = 0; k < HID; k++) pd += xr[k] * Wd[k * MSG + tid];
        float acc = 0.f;
        int s0 = ptr[d], s1 = ptr[d + 1];
        for (int i = s0; i < s1; i++) {
            int eid = elist[i];
            int s = slist[i];
            float eav = (lane < EDIM) ? ea[(size_t)eid * EDIM + lane] : 0.f;
            float pv = Ps[(size_t)s * MSG + tid];
            float pe = 0.f;
#pragma unroll
            for (int k = 0; k < EDIM; k++) pe += __shfl(eav, k) * We[k * MSG + tid];
            acc += fmaxf(pd + pv + pe, 0.f);
        }
        H[(size_t)d * MSG + tid] = acc;
        __syncthreads();
    }
}

// ---------------- m = H @ W_m2 + deg*b_m2, wave-per-node, block = 256 ----------------
__global__ void k_msg(const float* __restrict__ H, const float* __restrict__ Wm2,
                      const float* __restrict__ bm2, const int* __restrict__ ptr,
                      float* __restrict__ m, int N) {
    __shared__ float W2[MSG * HID];
    for (int t = threadIdx.x; t < MSG * HID; t += blockDim.x) W2[t] = Wm2[t];
    __syncthreads();
    int wv = threadIdx.x >> 6, lane = threadIdx.x & 63;
    int nw = blockDim.x >> 6;
    for (int d = blockIdx.x * nw + wv; d < N; d += gridDim.x * nw) {
        float h0 = H[(size_t)d * MSG + lane];
        float h1 = H[(size_t)d * MSG + 64 + lane];
        float deg = (float)(ptr[d + 1] - ptr[d]);
        float acc = deg * bm2[lane];
#pragma unroll
        for (int k = 0; k < 64; k++) acc += __shfl(h0, k) * W2[k * HID + lane];
#pragma unroll
        for (int k = 0; k < 64; k++) acc += __shfl(h1, k) * W2[(64 + k) * HID + lane];
        m[(size_t)d * HID + lane] = acc;
    }
}

// ---------------- GRU cell, block = 256 (192 active rows) ----------------
// Weights staged in LDS as RNE-rounded bf16 (f32-accumulated): keeps LDS ~51KB.
__global__ void k_gru(const float* __restrict__ m, const float* __restrict__ Wih,
                      const float* __restrict__ Whh, const float* __restrict__ bih,
                      const float* __restrict__ bhh, float* __restrict__ xh, int N) {
    __shared__ u16 WT[64 * 192];  // transposed: WT[k*192+j] = Wih[j*64+k]
    __shared__ u16 UT[64 * 192];
    __shared__ float mr[64], hr[64], gil[192], ghl[192];
    for (int t = threadIdx.x; t < 64 * 192; t += blockDim.x) {
        int k = t / 192, j = t - k * 192;
        WT[t] = f2b(Wih[j * 64 + k]);
        UT[t] = f2b(Whh[j * 64 + k]);
    }
    __syncthreads();
    int tid = threadIdx.x;
    for (int d = blockIdx.x; d < N; d += gridDim.x) {
        if (tid < 64) mr[tid] = m[(size_t)d * 64 + tid];
        else if (tid < 128) hr[tid - 64] = xh[(size_t)d * 64 + tid - 64];
        __syncthreads();
        if (tid < 192) {
            float gi = bih[tid];
            float gh = bhh[tid];
#pragma unroll
            for (int k = 0; k < 64; k++) {
                gi += mr[k] * b2f(WT[k * 192 + tid]);
                gh += hr[k] * b2f(UT[k * 192 + tid]);
            }
            gil[tid] = gi; ghl[tid] = gh;
        }
        __syncthreads();
        if (tid < 64) {
            float r = sigm(gil[tid] + ghl[tid]);
            float z = sigm(gil[64 + tid] + ghl[64 + tid]);
            float nn = tanhf(gil[128 + tid] + r * ghl[128 + tid]);
            xh[(size_t)d * 64 + tid] = (1.f - z) * nn + z * hr[tid];
        }
        __syncthreads();
    }
}

// ---------------- Set2Set LSTM cell, one block per graph, block = 256 ----------------
__global__ void k_lstm(float* __restrict__ qstar, float* __restrict__ qh, float* __restrict__ qc,
                       const float* __restrict__ Wih, const float* __restrict__ Whh,
                       const float* __restrict__ bih, const float* __restrict__ bhh) {
    int b = blockIdx.x, tid = threadIdx.x;
    __shared__ float qs[128], qhl[64], g[256];
    if (tid < 128) qs[tid] = qstar[b * 128 + tid];
    else if (tid < 192) qhl[tid - 128] = qh[b * 64 + tid - 128];
    __syncthreads();
    float acc = bih[tid] + bhh[tid];
    const float* wr = Wih + tid * 128;
#pragma unroll 8
    for (int k = 0; k < 128; k++) acc += qs[k] * wr[k];
    const float* ur = Whh + tid * 64;
#pragma unroll 8
    for (int k = 0; k < 64; k++) acc += qhl[k] * ur[k];
    g[tid] = acc;
    __syncthreads();
    if (tid < 64) {
        float ig = sigm(g[tid]), fg = sigm(g[64 + tid]);
        float gg = tanhf(g[128 + tid]), og = sigm(g[192 + tid]);
        float c = fg * qc[b * 64 + tid] + ig * gg;
        float h = og * tanhf(c);
        qc[b * 64 + tid] = c;
        qh[b * 64 + tid] = h;
        qstar[b * 128 + tid] = h;
    }
}

// ---------------- segment softmax attention + readout, one block per graph ----------------
__global__ void k_attn(const float* __restrict__ xh, const float* __restrict__ qh,
                       const int* __restrict__ gptr, float* __restrict__ qstar) {
    int b = blockIdx.x, tid = threadIdx.x;
    int grp = tid >> 6, lane = tid & 63;
    int start = gptr[b], end = gptr[b + 1];
    float qv = qh[b * 64 + lane];
    __shared__ float red[4];
    __shared__ float asums[4];
    __shared__ float rvs[256];
    float mloc = -3.4e38f;
    for (int n = start + grp; n < end; n += 4) {
        float xv = xh[(size_t)n * 64 + lane];
        float p = xv * qv;
#pragma unroll
        for (int off = 32; off > 0; off >>= 1) p += __shfl_xor(p, off);
        mloc = fmaxf(mloc, p);
    }
    if (lane == 0) red[grp] = mloc;
    __syncthreads();
    float emax = fmaxf(fmaxf(red[0], red[1]), fmaxf(red[2], red[3]));
    float asl = 0.f, rv = 0.f;
    for (int n = start + grp; n < end; n += 4) {
        float xv = xh[(size_t)n * 64 + lane];
        float p = xv * qv;
#pragma unroll
        for (int off = 32; off > 0; off >>= 1) p += __shfl_xor(p, off);
        float a = expf(p - emax);
        asl += a;
        rv += a * xv;
    }
    if (lane == 0) asums[grp] = asl;
    rvs[tid] = rv;
    __syncthreads();
    if (tid < 64) {
        float rt = rvs[tid] + rvs[64 + tid] + rvs[128 + tid] + rvs[192 + tid];
        float at = asums[0] + asums[1] + asums[2] + asums[3];
        qstar[b * 128 + 64 + tid] = (at > 0.f) ? rt / at : 0.f;
    }
}

// ---------------- final regressor, one wave per graph ----------------
__global__ void k_final(const float* __restrict__ qstar, const float* __restrict__ Wr1,
                        const float* __restrict__ br1, const float* __restrict__ Wr2,
                        const float* __restrict__ br2, float* __restrict__ out) {
    int b = blockIdx.x, j = threadIdx.x;
    float acc = br1[j];
#pragma unroll 8
    for (int k = 0; k < 128; k++) acc += qstar[b * 128 + k] * Wr1[k * 64 + j];
    acc = fmaxf(acc, 0.f);
    float v = acc * Wr2[j];
#pragma unroll
    for (int off = 32; off > 0; off >>= 1) v += __shfl_xor(v, off);
    if (j == 0) out[b] = v + br2[0];
}

extern "C" void kernel_launch(void* const* d_in, const int* in_sizes, int n_in,
                              void* d_out, int out_size, void* d_ws, size_t ws_size,
                              hipStream_t stream) {
    const float* x_feat = (const float*)d_in[0];
    const int*   ei     = (const int*)d_in[1];
    const float* eattr  = (const float*)d_in[2];
    const int*   batch  = (const int*)d_in[3];
    const float* W_emb  = (const float*)d_in[4];
    const float* b_emb  = (const float*)d_in[5];
    const float* W_m1   = (const float*)d_in[6];
    const float* b_m1   = (const float*)d_in[7];
    const float* W_m2   = (const float*)d_in[8];
    const float* b_m2   = (const float*)d_in[9];
    const float* gWih   = (const float*)d_in[10];
    const float* gWhh   = (const float*)d_in[11];
    const float* gbih   = (const float*)d_in[12];
    const float* gbhh   = (const float*)d_in[13];
    const float* lWih   = (const float*)d_in[14];
    const float* lWhh   = (const float*)d_in[15];
    const float* lbih   = (const float*)d_in[16];
    const float* lbhh   = (const float*)d_in[17];
    const float* Wr1    = (const float*)d_in[18];
    const float* br1    = (const float*)d_in[19];
    const float* Wr2    = (const float*)d_in[20];
    const float* br2    = (const float*)d_in[21];

    int N = in_sizes[0] / NDIM;   // 50000
    int E = in_sizes[1] / 2;      // 800000

    char* w = (char*)d_ws;
    auto alloc = [&](size_t b) { char* p = w; w += (b + 511) & ~(size_t)511; return p; };
    float* xh    = (float*)alloc((size_t)N * 64 * 4);
    float* Ps    = (float*)alloc((size_t)N * 128 * 4);
    float* Hb    = (float*)alloc((size_t)N * 128 * 4);
    float* mb    = (float*)alloc((size_t)N * 64 * 4);
    int*   ptr   = (int*)alloc((size_t)(N + 1) * 4);
    int*   elist = (int*)alloc((size_t)E * 4);
    int*   slist = (int*)alloc((size_t)E * 4);
    char* z0 = w;
    int*   cnt    = (int*)alloc((size_t)N * 4);
    int*   cursor = (int*)alloc((size_t)N * 4);
    int*   gcnt   = (int*)alloc((size_t)NG * 4);
    char* z0e = w;
    int*   gptr  = (int*)alloc((size_t)(NG + 1) * 4);
    char* z1 = w;
    float* qh    = (float*)alloc((size_t)NG * 64 * 4);
    float* qc    = (float*)alloc((size_t)NG * 64 * 4);
    float* qstar = (float*)alloc((size_t)NG * 128 * 4);
    char* z1e = w;

    hipMemsetAsync(z0, 0, (size_t)(z0e - z0), stream);
    hipMemsetAsync(z1, 0, (size_t)(z1e - z1), stream);

    k_hist<<<3125, 256, 0, stream>>>(ei + E, E, cnt);       // dst histogram
    k_hist<<<196, 256, 0, stream>>>(batch, N, gcnt);        // graph histogram
    k_scan<<<1, 1024, 0, stream>>>(cnt, ptr, N);
    k_scan<<<1, 1024, 0, stream>>>(gcnt, gptr, NG);
    k_scatter<<<3125, 256, 0, stream>>>(ei, ei + E, E, ptr, cursor, elist, slist);

    k_embed<<<4096, 256, 0, stream>>>(x_feat, W_emb, b_emb, xh, N);

    for (int r = 0; r < 3; r++) {
        k_ps<<<2048, 128, 0, stream>>>(xh, W_m1, Ps, N);
        k_edge<<<4096, 128, 0, stream>>>(xh, Ps, eattr, W_m1, b_m1, ptr, elist, slist, Hb, N);
        k_msg<<<1024, 256, 0, stream>>>(Hb, W_m2, b_m2, ptr, mb, N);
        k_gru<<<1024, 256, 0, stream>>>(mb, gWih, gWhh, gbih, gbhh, xh, N);
    }
    for (int s = 0; s < 6; s++) {
        k_lstm<<<NG, 256, 0, stream>>>(qstar, qh, qc, lWih, lWhh, lbih, lbhh);
        k_attn<<<NG, 256, 0, stream>>>(xh, qh, gptr, qstar);
    }
    k_final<<<NG, 64, 0, stream>>>(qstar, Wr1, br1, Wr2, br2, (float*)d_out);
}

// Round 3
// 3032.520 us; speedup vs baseline: 1.7673x; 1.7673x over previous
//
#include <hip/hip_runtime.h>
#include <hip/hip_bf16.h>

#define HID 64
#define MSG 128
#define NDIM 32
#define EDIM 16
#define NG 512

typedef unsigned short u16;

__device__ __forceinline__ float b2f(u16 u) {
    union { unsigned int i; float f; } v; v.i = ((unsigned int)u) << 16; return v.f;
}
__device__ __forceinline__ u16 f2b(float f) {
    union { float f; unsigned int i; } v; v.f = f;
    unsigned int r = v.i + 0x7FFF + ((v.i >> 16) & 1);
    return (u16)(r >> 16);
}
__device__ __forceinline__ unsigned int pack2(float a, float b) {
    return (unsigned int)f2b(a) | ((unsigned int)f2b(b) << 16);
}
__device__ __forceinline__ float sigm(float x) { return 1.0f / (1.0f + expf(-x)); }

// ---------------- CSR build ----------------
__global__ void k_hist(const int* __restrict__ idx, int n, int* __restrict__ cnt) {
    int i = blockIdx.x * blockDim.x + threadIdx.x;
    int stride = gridDim.x * blockDim.x;
    for (; i < n; i += stride) atomicAdd(&cnt[idx[i]], 1);
}

// single-block chunked exclusive scan, out[n] = total. block = 1024.
__global__ void k_scan(const int* __restrict__ in, int* __restrict__ out, int n) {
    __shared__ int sums[1024];
    int tid = threadIdx.x;
    int chunk = (n + 1023) >> 10;
    int begin = tid * chunk;
    int endp = begin + chunk; if (endp > n) endp = n;
    int s = 0;
    for (int i = begin; i < endp; i++) s += in[i];
    sums[tid] = s;
    __syncthreads();
    for (int off = 1; off < 1024; off <<= 1) {
        int t = (tid >= off) ? sums[tid - off] : 0;
        __syncthreads();
        sums[tid] += t;
        __syncthreads();
    }
    int run = sums[tid] - s;  // exclusive prefix of this chunk
    for (int i = begin; i < endp; i++) { out[i] = run; run += in[i]; }
    if (tid == 1023) out[n] = sums[1023];
}

// gptr via binary search in sorted batch
__global__ void k_gptr(const int* __restrict__ batch, int N, int* __restrict__ gptr) {
    int g = blockIdx.x * blockDim.x + threadIdx.x;
    if (g > NG) return;
    int lo = 0, hi = N;
    while (lo < hi) { int mid = (lo + hi) >> 1; if (batch[mid] < g) lo = mid + 1; else hi = mid; }
    gptr[g] = lo;
}

__global__ void k_scatter(const int* __restrict__ src, const int* __restrict__ dst, int n,
                          const int* __restrict__ ptr, int* __restrict__ cursor,
                          int2* __restrict__ esl) {
    int i = blockIdx.x * blockDim.x + threadIdx.x;
    int stride = gridDim.x * blockDim.x;
    for (; i < n; i += stride) {
        int d = dst[i];
        int pos = ptr[d] + atomicAdd(&cursor[d], 1);
        esl[pos] = make_int2(i, src[i]);
    }
}

// ---------------- node embedding: xh = x_feat @ W_emb + b_emb ----------------
__global__ void k_embed(const float* __restrict__ xf, const float* __restrict__ We,
                        const float* __restrict__ be, float* __restrict__ xh, int N) {
    __shared__ float Wl[NDIM * HID];
    for (int t = threadIdx.x; t < NDIM * HID; t += blockDim.x) Wl[t] = We[t];
    __syncthreads();
    int total = N * HID;
    int stride = gridDim.x * blockDim.x;
    for (int idx = blockIdx.x * blockDim.x + threadIdx.x; idx < total; idx += stride) {
        int n = idx >> 6, c = idx & 63;
        const float* xr = xf + n * NDIM;
        float acc = be[c];
#pragma unroll
        for (int k = 0; k < NDIM; k++) acc += xr[k] * Wl[k * HID + c];
        xh[idx] = acc;
    }
}

// ---------------- k_prep: Pd (-> Hb) and Ps, dense GEMM [N,64]@[64,256] ----------------
// Wl combined: Wl[k*256+cc] = (cc<128 ? Wm1[k][cc] : Wm1[64+k][cc-128])
__global__ void k_prep(const float* __restrict__ xh, const float* __restrict__ Wm1,
                       const float* __restrict__ bm1, float* __restrict__ Hb,
                       float* __restrict__ Ps, int N) {
    __shared__ float Wl[64 * 256];
    __shared__ float xl[256];
    for (int t = threadIdx.x; t < 64 * 256; t += blockDim.x) {
        int k = t >> 8, cc = t & 255;
        Wl[t] = (cc < 128) ? Wm1[k * 128 + cc] : Wm1[(64 + k) * 128 + (cc - 128)];
    }
    __syncthreads();
    int nl = threadIdx.x >> 6;   // 0..3 node within tile
    int cq = threadIdx.x & 63;   // float4 group of 256 combined channels
    int cc = cq << 2;
    for (int base = blockIdx.x * 4; base < N; base += gridDim.x * 4) {
        __syncthreads();
        int gi = base * 64 + threadIdx.x;
        if (gi < N * 64) xl[threadIdx.x] = xh[gi];
        __syncthreads();
        int d = base + nl;
        if (d < N) {
            float4 acc;
            if (cc < 128) acc = *(const float4*)&bm1[cc];
            else acc = make_float4(0.f, 0.f, 0.f, 0.f);
#pragma unroll
            for (int k = 0; k < 64; k++) {
                float xv = xl[nl * 64 + k];
                float4 w = *(const float4*)&Wl[k * 256 + cc];
                acc.x += xv * w.x; acc.y += xv * w.y; acc.z += xv * w.z; acc.w += xv * w.w;
            }
            if (cc < 128) *(float4*)&Hb[(size_t)d * 128 + cc] = acc;
            else *(float4*)&Ps[(size_t)d * 128 + (cc - 128)] = acc;
        }
    }
}

// ---------------- k_edge: H[d] = sum_e relu(Pd[d] + Ps[src] + W1e@ea) ----------------
// Pd arrives in Hb and is overwritten with the result. block = 256 = 2 nodes x 128 ch.
__global__ void __launch_bounds__(256, 8)
k_edge(const float* __restrict__ Ps, const float* __restrict__ ea,
       const float* __restrict__ Wm1, const int* __restrict__ ptr,
       const int2* __restrict__ esl, float* __restrict__ Hb, int N) {
    __shared__ float We[EDIM * MSG];
    for (int t = threadIdx.x; t < EDIM * MSG; t += blockDim.x) We[t] = Wm1[MSG * MSG + t];
    __syncthreads();
    int half = threadIdx.x >> 7;
    int c = threadIdx.x & 127;
    int lane = threadIdx.x & 63;
    for (int d = blockIdx.x * 2 + half; d < N; d += gridDim.x * 2) {
        float pd = Hb[(size_t)d * 128 + c];
        float acc = 0.f;
        int s0 = ptr[d], s1 = ptr[d + 1];
        int i = s0;
        for (; i + 4 <= s1; i += 4) {
            int2 q = esl[i + (lane >> 4)];
            float eav = ea[(size_t)q.x * EDIM + (lane & 15)];
            int sA = __shfl(q.y, 0), sB = __shfl(q.y, 16);
            int sC = __shfl(q.y, 32), sD = __shfl(q.y, 48);
            float pvA = Ps[(size_t)sA * 128 + c];
            float pvB = Ps[(size_t)sB * 128 + c];
            float pvC = Ps[(size_t)sC * 128 + c];
            float pvD = Ps[(size_t)sD * 128 + c];
            float peA = 0.f, peB = 0.f, peC = 0.f, peD = 0.f;
#pragma unroll
            for (int k = 0; k < EDIM; k++) {
                float w = We[k * MSG + c];
                peA += __shfl(eav, k) * w;
                peB += __shfl(eav, 16 + k) * w;
                peC += __shfl(eav, 32 + k) * w;
                peD += __shfl(eav, 48 + k) * w;
            }
            acc += fmaxf(pd + pvA + peA, 0.f) + fmaxf(pd + pvB + peB, 0.f)
                 + fmaxf(pd + pvC + peC, 0.f) + fmaxf(pd + pvD + peD, 0.f);
        }
        for (; i < s1; i++) {
            int2 q = esl[i];
            float eav = (lane < EDIM) ? ea[(size_t)q.x * EDIM + lane] : 0.f;
            float pv = Ps[(size_t)q.y * 128 + c];
            float pe = 0.f;
#pragma unroll
            for (int k = 0; k < EDIM; k++) pe += __shfl(eav, k) * We[k * MSG + c];
            acc += fmaxf(pd + pv + pe, 0.f);
        }
        Hb[(size_t)d * 128 + c] = acc;
    }
}

// ---------------- m = H @ W_m2 + deg*b_m2, wave-per-node ----------------
__global__ void k_msg(const float* __restrict__ H, const float* __restrict__ Wm2,
                      const float* __restrict__ bm2, const int* __restrict__ ptr,
                      float* __restrict__ m, int N) {
    __shared__ float W2[MSG * HID];
    for (int t = threadIdx.x; t < MSG * HID; t += blockDim.x) W2[t] = Wm2[t];
    __syncthreads();
    int wv = threadIdx.x >> 6, lane = threadIdx.x & 63;
    int nw = blockDim.x >> 6;
    float b2 = bm2[lane];
    for (int d = blockIdx.x * nw + wv; d < N; d += gridDim.x * nw) {
        float h0 = H[(size_t)d * MSG + lane];
        float h1 = H[(size_t)d * MSG + 64 + lane];
        float deg = (float)(ptr[d + 1] - ptr[d]);
        float acc = deg * b2;
#pragma unroll
        for (int k = 0; k < 64; k++) acc += __shfl(h0, k) * W2[k * HID + lane];
#pragma unroll
        for (int k = 0; k < 64; k++) acc += __shfl(h1, k) * W2[(64 + k) * HID + lane];
        m[(size_t)d * HID + lane] = acc;
    }
}

// ---------------- GRU cell, wave-per-node, packed bf16 gate-triples in LDS ----------------
__global__ void k_gru(const float* __restrict__ m, const float* __restrict__ Wih,
                      const float* __restrict__ Whh, const float* __restrict__ bih,
                      const float* __restrict__ bhh, float* __restrict__ xh, int N) {
    __shared__ uint4 Wp[64 * 64];  // [k][c]: {Wr,Wz | Wn,Ur | Uz,Un | 0}
    for (int t = threadIdx.x; t < 64 * 64; t += blockDim.x) {
        int k = t >> 6, c = t & 63;
        uint4 w;
        w.x = pack2(Wih[c * 64 + k],         Wih[(64 + c) * 64 + k]);
        w.y = pack2(Wih[(128 + c) * 64 + k], Whh[c * 64 + k]);
        w.z = pack2(Whh[(64 + c) * 64 + k],  Whh[(128 + c) * 64 + k]);
        w.w = 0;
        Wp[t] = w;
    }
    __syncthreads();
    int wv = threadIdx.x >> 6, lane = threadIdx.x & 63;
    float br = bih[lane], bz = bih[64 + lane], bn = bih[128 + lane];
    float cr = bhh[lane], cz = bhh[64 + lane], cn = bhh[128 + lane];
    for (int d = blockIdx.x * 4 + wv; d < N; d += gridDim.x * 4) {
        float mv = m[(size_t)d * 64 + lane];
        float hv = xh[(size_t)d * 64 + lane];
        float gir = br, giz = bz, gin = bn;
        float ghr = cr, ghz = cz, ghn = cn;
#pragma unroll 8
        for (int k = 0; k < 64; k++) {
            float mk = __shfl(mv, k), hk = __shfl(hv, k);
            uint4 w = Wp[k * 64 + lane];
            gir += mk * b2f((u16)w.x); giz += mk * b2f((u16)(w.x >> 16));
            gin += mk * b2f((u16)w.y); ghr += hk * b2f((u16)(w.y >> 16));
            ghz += hk * b2f((u16)w.z); ghn += hk * b2f((u16)(w.z >> 16));
        }
        float r = sigm(gir + ghr);
        float z = sigm(giz + ghz);
        float nn = tanhf(gin + r * ghn);
        xh[(size_t)d * 64 + lane] = (1.f - z) * nn + z * hv;
    }
}

// ---------------- fused Set2Set step: LSTM cell + attention (+ final on last) ----------------
__global__ void k_s2s(const float* __restrict__ xh, const int* __restrict__ gptr,
                      float* __restrict__ qstar, float* __restrict__ qh, float* __restrict__ qc,
                      const float* __restrict__ lWih, const float* __restrict__ lWhh,
                      const float* __restrict__ lbih, const float* __restrict__ lbhh,
                      const float* __restrict__ Wr1, const float* __restrict__ br1,
                      const float* __restrict__ Wr2, const float* __restrict__ br2,
                      float* __restrict__ out, int last) {
    int b = blockIdx.x, tid = threadIdx.x;
    __shared__ float qs[128], qhl[64], g[256], red[4], asums[4], rvs[256];
    if (tid < 128) qs[tid] = qstar[b * 128 + tid];
    else if (tid < 192) qhl[tid - 128] = qh[b * 64 + tid - 128];
    __syncthreads();
    // LSTM gate pre-activation, one per thread (order i,f,g,o)
    float acc = lbih[tid] + lbhh[tid];
    const float* wr = lWih + tid * 128;
#pragma unroll 8
    for (int k = 0; k < 128; k++) acc += qs[k] * wr[k];
    const float* ur = lWhh + tid * 64;
#pragma unroll 8
    for (int k = 0; k < 64; k++) acc += qhl[k] * ur[k];
    g[tid] = acc;
    __syncthreads();
    if (tid < 64) {
        float ig = sigm(g[tid]), fg = sigm(g[64 + tid]);
        float gg = tanhf(g[128 + tid]), og = sigm(g[192 + tid]);
        float c = fg * qc[b * 64 + tid] + ig * gg;
        float h = og * tanhf(c);
        qc[b * 64 + tid] = c;
        qh[b * 64 + tid] = h;
        qstar[b * 128 + tid] = h;
        qhl[tid] = h;
        qs[tid] = h;  // for final regressor
    }
    __syncthreads();
    // attention over this graph's node segment
    int grp = tid >> 6, lane = tid & 63;
    int start = gptr[b], end = gptr[b + 1];
    float qv = qhl[lane];
    float mloc = -3.4e38f;
    for (int n = start + grp; n < end; n += 4) {
        float p = xh[(size_t)n * 64 + lane] * qv;
#pragma unroll
        for (int off = 32; off > 0; off >>= 1) p += __shfl_xor(p, off);
        mloc = fmaxf(mloc, p);
    }
    if (lane == 0) red[grp] = mloc;
    __syncthreads();
    float emax = fmaxf(fmaxf(red[0], red[1]), fmaxf(red[2], red[3]));
    float asl = 0.f, rv = 0.f;
    for (int n = start + grp; n < end; n += 4) {
        float xv = xh[(size_t)n * 64 + lane];
        float p = xv * qv;
#pragma unroll
        for (int off = 32; off > 0; off >>= 1) p += __shfl_xor(p, off);
        float a = expf(p - emax);
        asl += a;
        rv += a * xv;
    }
    if (lane == 0) asums[grp] = asl;
    rvs[tid] = rv;
    __syncthreads();
    if (tid < 64) {
        float rt = rvs[tid] + rvs[64 + tid] + rvs[128 + tid] + rvs[192 + tid];
        float at = asums[0] + asums[1] + asums[2] + asums[3];
        float rvec = (at > 0.f) ? rt / at : 0.f;
        qstar[b * 128 + 64 + tid] = rvec;
        qs[64 + tid] = rvec;
    }
    if (last) {
        __syncthreads();
        if (tid < 64) {
            float a2 = br1[tid];
#pragma unroll 8
            for (int k = 0; k < 128; k++) a2 += qs[k] * Wr1[k * 64 + tid];
            a2 = fmaxf(a2, 0.f);
            float v = a2 * Wr2[tid];
#pragma unroll
            for (int off = 32; off > 0; off >>= 1) v += __shfl_xor(v, off);
            if (tid == 0) out[b] = v + br2[0];
        }
    }
}

extern "C" void kernel_launch(void* const* d_in, const int* in_sizes, int n_in,
                              void* d_out, int out_size, void* d_ws, size_t ws_size,
                              hipStream_t stream) {
    const float* x_feat = (const float*)d_in[0];
    const int*   ei     = (const int*)d_in[1];
    const float* eattr  = (const float*)d_in[2];
    const int*   batch  = (const int*)d_in[3];
    const float* W_emb  = (const float*)d_in[4];
    const float* b_emb  = (const float*)d_in[5];
    const float* W_m1   = (const float*)d_in[6];
    const float* b_m1   = (const float*)d_in[7];
    const float* W_m2   = (const float*)d_in[8];
    const float* b_m2   = (const float*)d_in[9];
    const float* gWih   = (const float*)d_in[10];
    const float* gWhh   = (const float*)d_in[11];
    const float* gbih   = (const float*)d_in[12];
    const float* gbhh   = (const float*)d_in[13];
    const float* lWih   = (const float*)d_in[14];
    const float* lWhh   = (const float*)d_in[15];
    const float* lbih   = (const float*)d_in[16];
    const float* lbhh   = (const float*)d_in[17];
    const float* Wr1    = (const float*)d_in[18];
    const float* br1    = (const float*)d_in[19];
    const float* Wr2    = (const float*)d_in[20];
    const float* br2    = (const float*)d_in[21];

    int N = in_sizes[0] / NDIM;   // 50000
    int E = in_sizes[1] / 2;      // 800000

    char* w = (char*)d_ws;
    auto alloc = [&](size_t b) { char* p = w; w += (b + 511) & ~(size_t)511; return p; };
    float* xh    = (float*)alloc((size_t)N * 64 * 4);
    float* Ps    = (float*)alloc((size_t)N * 128 * 4);
    float* Hb    = (float*)alloc((size_t)N * 128 * 4);
    float* mb    = (float*)alloc((size_t)N * 64 * 4);
    int*   ptr   = (int*)alloc((size_t)(N + 1) * 4);
    int2*  esl   = (int2*)alloc((size_t)E * 8);
    char* z0 = w;
    int*   cnt    = (int*)alloc((size_t)N * 4);
    int*   cursor = (int*)alloc((size_t)N * 4);
    char* z0e = w;
    int*   gptr  = (int*)alloc((size_t)(NG + 1) * 4);
    char* z1 = w;
    float* qh    = (float*)alloc((size_t)NG * 64 * 4);
    float* qc    = (float*)alloc((size_t)NG * 64 * 4);
    float* qstar = (float*)alloc((size_t)NG * 128 * 4);
    char* z1e = w;

    hipMemsetAsync(z0, 0, (size_t)(z0e - z0), stream);
    hipMemsetAsync(z1, 0, (size_t)(z1e - z1), stream);

    k_hist<<<1024, 256, 0, stream>>>(ei + E, E, cnt);
    k_scan<<<1, 1024, 0, stream>>>(cnt, ptr, N);
    k_gptr<<<3, 256, 0, stream>>>(batch, N, gptr);
    k_scatter<<<3125, 256, 0, stream>>>(ei, ei + E, E, ptr, cursor, esl);

    k_embed<<<2048, 256, 0, stream>>>(x_feat, W_emb, b_emb, xh, N);

    for (int r = 0; r < 3; r++) {
        k_prep<<<2048, 256, 0, stream>>>(xh, W_m1, b_m1, Hb, Ps, N);
        k_edge<<<4096, 256, 0, stream>>>(Ps, eattr, W_m1, ptr, esl, Hb, N);
        k_msg<<<2048, 256, 0, stream>>>(Hb, W_m2, b_m2, ptr, mb, N);
        k_gru<<<2048, 256, 0, stream>>>(mb, gWih, gWhh, gbih, gbhh, xh, N);
    }
    for (int s = 0; s < 6; s++) {
        k_s2s<<<NG, 256, 0, stream>>>(xh, gptr, qstar, qh, qc,
                                      lWih, lWhh, lbih, lbhh,
                                      Wr1, br1, Wr2, br2, (float*)d_out, s == 5);
    }
}